// Round 5
// baseline (395.297 us; speedup 1.0000x reference)
//
#include <hip/hip_runtime.h>

typedef unsigned short ushort_t;
typedef __attribute__((ext_vector_type(8))) __bf16 bf16x8;
typedef __attribute__((ext_vector_type(4))) float floatx4;

__device__ __forceinline__ ushort_t f2bf(float f) {
    unsigned int u = __builtin_bit_cast(unsigned int, f);
    u = (u + 0x7fffu + ((u >> 16) & 1u)) >> 16;
    return (ushort_t)u;
}

__device__ __forceinline__ void async16(const ushort_t* g, ushort_t* l) {
    __builtin_amdgcn_global_load_lds(
        (const __attribute__((address_space(1))) unsigned int*)g,
        (__attribute__((address_space(3))) unsigned int*)l,
        16 /*bytes*/, 0 /*offset*/, 0 /*aux*/);
}

// XOR-swizzled LDS offset (ushort index) of the 8-elem group (row, cg).
__device__ __forceinline__ int sw(int row, int cg) {
    return ((row << 2) + ((cg ^ row ^ (row >> 2)) & 3)) << 3;
}

// ---------------------------------------------------------------------------
// Producer/consumer pipelined bf16 GEMM core. 576 threads:
//   wave 8   = producer: streams global->LDS, ~3 ksteps (48KB) in flight,
//              publishes `ready` (ksteps complete) after s_waitcnt vmcnt(32).
//   waves 0-7= consumers: 2(m) x 4(n) grid, 64x32 wave tile, IM4 x IN2
//              mfma_16x16x32. Poll `ready` (acquire), never wait on vmcnt.
// DEPTH=3 LDS ring: slot k%3 holds A(8KB)+B(8KB) of kstep k. Slot reuse gated
// on consumers' `done` counter (release). No s_barrier in the K-loop at all.
// ---------------------------------------------------------------------------
__device__ __forceinline__ void pipe_gemm(
    const ushort_t* __restrict__ A, int lda,
    const ushort_t* __restrict__ B, int ldb,
    int nk, int tile_m, int tile_n,
    ushort_t* buf, int* ready, int* done,
    floatx4 (&acc)[4][2]) {

    const int tid = threadIdx.x;

    if (tid == 0) {
        *ready = 0;
        *done = 0;
    }
    __syncthreads();  // only barrier: flag init visibility

    if (tid >= 512) {
        // ---------------- producer wave ----------------
        const int lane = tid & 63;
        const int row0 = lane >> 2;                                  // 0..15
        const int cg   = ((lane & 3) ^ row0 ^ (row0 >> 2)) & 3;      // invariant over i
        const ushort_t* pA = A + (long)(tile_m + row0) * lda + cg * 8;
        const ushort_t* pB = B + (long)(tile_n + row0) * ldb + cg * 8;

        for (int k = 0; k < nk; ++k) {
            const int slot = k % 3;
            if (k >= 3) {
                // wait until all 8 consumers finished kstep k-3 (slot reuse)
                while (__hip_atomic_load(done, __ATOMIC_ACQUIRE,
                                         __HIP_MEMORY_SCOPE_WORKGROUP) < 8 * (k - 2))
                    __builtin_amdgcn_s_sleep(1);
            }
            const ushort_t* ga = pA + k * 32;
            const ushort_t* gb = pB + k * 32;
            ushort_t* la = &buf[slot * 8192 + (tid & 63) * 8];
#pragma unroll
            for (int i = 0; i < 8; ++i) {
                async16(ga + (long)i * 16 * lda, la + i * 512);
                async16(gb + (long)i * 16 * ldb, la + 4096 + i * 512);
            }
            if (k >= 2) {
                asm volatile("s_waitcnt vmcnt(32)" ::: "memory");
                __hip_atomic_store(ready, k - 1, __ATOMIC_RELEASE,
                                   __HIP_MEMORY_SCOPE_WORKGROUP);
            }
        }
        asm volatile("s_waitcnt vmcnt(16)" ::: "memory");
        __hip_atomic_store(ready, nk - 1, __ATOMIC_RELEASE,
                           __HIP_MEMORY_SCOPE_WORKGROUP);
        asm volatile("s_waitcnt vmcnt(0)" ::: "memory");
        __hip_atomic_store(ready, nk, __ATOMIC_RELEASE,
                           __HIP_MEMORY_SCOPE_WORKGROUP);
        return;
    }

    // ---------------- consumer waves ----------------
    const int lane = tid & 63;
    const int wave = tid >> 6;            // 0..7
    const int wm   = wave >> 2;           // 0..1
    const int wn   = wave & 3;            // 0..3
    const int quad = lane >> 4;
    const int l16  = lane & 15;

#pragma unroll
    for (int i = 0; i < 4; i++)
#pragma unroll
        for (int j = 0; j < 2; j++) acc[i][j] = (floatx4){0.f, 0.f, 0.f, 0.f};

    for (int k = 0; k < nk; ++k) {
        while (__hip_atomic_load(ready, __ATOMIC_ACQUIRE,
                                 __HIP_MEMORY_SCOPE_WORKGROUP) < k + 1)
            __builtin_amdgcn_s_sleep(1);

        const ushort_t* as = &buf[(k % 3) * 8192];
        const ushort_t* bs = as + 4096;

        bf16x8 af[4], bfr[2];
#pragma unroll
        for (int im = 0; im < 4; im++)
            af[im] = *(const bf16x8*)&as[sw(wm * 64 + im * 16 + l16, quad)];
#pragma unroll
        for (int in = 0; in < 2; in++)
            bfr[in] = *(const bf16x8*)&bs[sw(wn * 32 + in * 16 + l16, quad)];
#pragma unroll
        for (int im = 0; im < 4; im++)
#pragma unroll
            for (int in = 0; in < 2; in++)
                acc[im][in] = __builtin_amdgcn_mfma_f32_16x16x32_bf16(
                    af[im], bfr[in], acc[im][in], 0, 0, 0);

        if (lane == 0)
            __hip_atomic_fetch_add(done, 1, __ATOMIC_RELEASE,
                                   __HIP_MEMORY_SCOPE_WORKGROUP);
    }
}

// ---------------------------------------------------------------------------
// fp32 -> bf16 conversion for x, W_q, W_k, W_v ; trailing blocks zero lsum
// ---------------------------------------------------------------------------
__global__ void cvt_kernel(const float* __restrict__ x,
                           const float* __restrict__ wq,
                           const float* __restrict__ wk,
                           const float* __restrict__ wv,
                           ushort_t* __restrict__ dst,
                           float* __restrict__ lsum) {
    if (blockIdx.x >= 11264) {
        int idx = (blockIdx.x - 11264) * 256 + threadIdx.x;  // [0,2048)
        ((float4*)lsum)[idx] = (float4){0.f, 0.f, 0.f, 0.f};
        return;
    }
    const long NX = 8388608, NW = 1048576;
    long g = ((long)blockIdx.x * blockDim.x + threadIdx.x) * 4;
    const float* src;
    long off;
    if (g < NX)             { src = x;  off = g; }
    else if (g < NX + NW)   { src = wq; off = g - NX; }
    else if (g < NX + 2*NW) { src = wk; off = g - NX - NW; }
    else                    { src = wv; off = g - NX - 2*NW; }
    float4 v = *(const float4*)(src + off);
    ushort4 o;
    o.x = f2bf(v.x); o.y = f2bf(v.y); o.z = f2bf(v.z); o.w = f2bf(v.w);
    *(ushort4*)(dst + g) = o;
}

// ---------------------------------------------------------------------------
// Fused projections: z=0 -> Q = x Wq^T, z=1 -> K = x Wk^T, z=2 -> V^T = Wv x^T
// ---------------------------------------------------------------------------
__global__ __launch_bounds__(576, 2) void qkv_kernel(
    const ushort_t* __restrict__ xb,
    const ushort_t* __restrict__ wqb,
    const ushort_t* __restrict__ wkb,
    const ushort_t* __restrict__ wvb,
    ushort_t* __restrict__ Qb,
    ushort_t* __restrict__ Kb,
    ushort_t* __restrict__ VTb) {

    __shared__ __align__(16) ushort_t buf[3 * 8192];
    __shared__ int s_ready, s_done;

    const int z = blockIdx.z;
    const ushort_t *A, *B;
    ushort_t* C;
    int ldc, tile_m, tile_n;
    if (z == 2) {  // V^T = Wv x^T : M=1024 (x), N=8192 (y)
        A = wvb; B = xb; C = VTb; ldc = 8192;
        tile_m = blockIdx.x * 128; tile_n = blockIdx.y * 128;
    } else {       // Q/K = x W^T : M=8192 (y), N=1024 (x)
        A = xb; B = z ? wkb : wqb; C = z ? Kb : Qb; ldc = 1024;
        tile_m = blockIdx.y * 128; tile_n = blockIdx.x * 128;
    }

    floatx4 acc[4][2];
    pipe_gemm(A, 1024, B, 1024, 32, tile_m, tile_n, buf, &s_ready, &s_done, acc);
    if (threadIdx.x >= 512) return;  // producer has no epilogue

    const int lane = threadIdx.x & 63, wave = threadIdx.x >> 6;
    const int wm = wave >> 2, wn = wave & 3, quad = lane >> 4, l16 = lane & 15;
#pragma unroll
    for (int im = 0; im < 4; im++)
#pragma unroll
        for (int r = 0; r < 4; r++) {
            int row = tile_m + wm * 64 + im * 16 + quad * 4 + r;
#pragma unroll
            for (int in = 0; in < 2; in++) {
                int col = tile_n + wn * 32 + in * 16 + l16;
                C[(long)row * ldc + col] = f2bf(acc[im][in][r]);
            }
        }
}

// ---------------------------------------------------------------------------
// P = exp(scale * Q K^T) per batch + fused row-sum atomics into lsum
// ---------------------------------------------------------------------------
__global__ __launch_bounds__(576, 2) void pexp_kernel(
    const ushort_t* __restrict__ Qb,
    const ushort_t* __restrict__ Kb,
    ushort_t* __restrict__ Pb,
    float* __restrict__ lsum) {

    __shared__ __align__(16) ushort_t buf[3 * 8192];
    __shared__ int s_ready, s_done;

    const int z = blockIdx.z;
    const ushort_t* A = Qb + (long)z * 2097152;
    const ushort_t* B = Kb + (long)z * 2097152;
    ushort_t* C = Pb + (long)z * 4194304;
    float* l = lsum + z * 2048;
    const int tile_m = blockIdx.y * 128;
    const int tile_n = blockIdx.x * 128;

    floatx4 acc[4][2];
    pipe_gemm(A, 1024, B, 1024, 32, tile_m, tile_n, buf, &s_ready, &s_done, acc);
    if (threadIdx.x >= 512) return;

    const float scale = 0.022097086912079608f;  // 1/sqrt(2048)
    const int lane = threadIdx.x & 63, wave = threadIdx.x >> 6;
    const int wm = wave >> 2, wn = wave & 3, quad = lane >> 4, l16 = lane & 15;
#pragma unroll
    for (int im = 0; im < 4; im++)
#pragma unroll
        for (int r = 0; r < 4; r++) {
            int row = tile_m + wm * 64 + im * 16 + quad * 4 + r;
            float psum = 0.f;
#pragma unroll
            for (int in = 0; in < 2; in++) {
                int col = tile_n + wn * 32 + in * 16 + l16;
                float e = __expf(acc[im][in][r] * scale);
                C[(long)row * 2048 + col] = f2bf(e);
                psum += e;
            }
            psum += __shfl_xor(psum, 1, 64);
            psum += __shfl_xor(psum, 2, 64);
            psum += __shfl_xor(psum, 4, 64);
            psum += __shfl_xor(psum, 8, 64);
            if (l16 == 0) atomicAdd(&l[row], psum);
        }
}

// ---------------------------------------------------------------------------
// out = (P V) / l per batch
// ---------------------------------------------------------------------------
__global__ __launch_bounds__(576, 2) void out_kernel(
    const ushort_t* __restrict__ Pb,
    const ushort_t* __restrict__ VTb,
    float* __restrict__ out,
    const float* __restrict__ lsum) {

    __shared__ __align__(16) ushort_t buf[3 * 8192];
    __shared__ int s_ready, s_done;

    const int z = blockIdx.z;
    const ushort_t* A = Pb + (long)z * 4194304;   // [2048][2048]
    const ushort_t* B = VTb + (long)z * 2048;     // ldb=8192, batch col slice
    float* C = out + (long)z * 2097152;
    const float* l = lsum + z * 2048;
    const int tile_m = blockIdx.y * 128;
    const int tile_n = blockIdx.x * 128;

    floatx4 acc[4][2];
    pipe_gemm(A, 2048, B, 8192, 64, tile_m, tile_n, buf, &s_ready, &s_done, acc);
    if (threadIdx.x >= 512) return;

    const int lane = threadIdx.x & 63, wave = threadIdx.x >> 6;
    const int wm = wave >> 2, wn = wave & 3, quad = lane >> 4, l16 = lane & 15;
#pragma unroll
    for (int im = 0; im < 4; im++)
#pragma unroll
        for (int r = 0; r < 4; r++) {
            int row = tile_m + wm * 64 + im * 16 + quad * 4 + r;
            float li = 1.0f / l[row];
#pragma unroll
            for (int in = 0; in < 2; in++) {
                int col = tile_n + wn * 32 + in * 16 + l16;
                C[(long)row * 1024 + col] = acc[im][in][r] * li;
            }
        }
}

// ---------------------------------------------------------------------------
extern "C" void kernel_launch(void* const* d_in, const int* in_sizes, int n_in,
                              void* d_out, int out_size, void* d_ws, size_t ws_size,
                              hipStream_t stream) {
    const float* x  = (const float*)d_in[0];
    const float* wq = (const float*)d_in[1];
    const float* wk = (const float*)d_in[2];
    const float* wv = (const float*)d_in[3];

    ushort_t* xb  = (ushort_t*)d_ws;          // [8192,1024] bf16
    ushort_t* wqb = xb  + 8388608;            // [1024,1024]
    ushort_t* wkb = wqb + 1048576;
    ushort_t* wvb = wkb + 1048576;
    ushort_t* Qb  = wvb + 1048576;            // [8192,1024]
    ushort_t* Kb  = Qb  + 8388608;            // [8192,1024]
    ushort_t* VTb = Kb  + 8388608;            // [1024,8192]
    ushort_t* Pb  = VTb + 8388608;            // [4][2048][2048]
    float*    lsum = (float*)(Pb + 16777216); // [4][2048] fp32 row sums
    float*    out  = (float*)d_out;

    // 1) fp32->bf16 (+ zero lsum in trailing 8 blocks)
    cvt_kernel<<<11272, 256, 0, stream>>>(x, wq, wk, wv, xb, lsum);

    // 2) Q, K, V^T in one dispatch (1536 blocks x 576 thr)
    qkv_kernel<<<dim3(8, 64, 3), 576, 0, stream>>>(xb, wqb, wkb, wvb, Qb, Kb, VTb);

    // 3) P = exp(scale * Q K^T) + row sums (1024 blocks)
    pexp_kernel<<<dim3(16, 16, 4), 576, 0, stream>>>(Qb, Kb, Pb, lsum);

    // 4) out = (P V) / l (512 blocks)
    out_kernel<<<dim3(8, 16, 4), 576, 0, stream>>>(Pb, VTb, out, lsum);
}

// Round 6
// 272.545 us; speedup vs baseline: 1.4504x; 1.4504x over previous
//
#include <hip/hip_runtime.h>

typedef unsigned short ushort_t;
typedef __attribute__((ext_vector_type(8))) __bf16 bf16x8;
typedef __attribute__((ext_vector_type(4))) float floatx4;

__device__ __forceinline__ ushort_t f2bf(float f) {
    unsigned int u = __builtin_bit_cast(unsigned int, f);
    u = (u + 0x7fffu + ((u >> 16) & 1u)) >> 16;
    return (ushort_t)u;
}

// XOR-swizzled LDS offset (ushort index) of the 8-elem group (row, cg).
__device__ __forceinline__ int sw(int row, int cg) {
    return ((row << 2) + ((cg ^ row ^ (row >> 2)) & 3)) << 3;
}

// ---------------------------------------------------------------------------
// VGPR-prefetch double-buffered bf16 GEMM core (hipBLASLt-style transport):
// 128x128 tile, 256 threads (4 waves 2x2), IM=IN=4 mfma_16x16x32.
// Per kstep: issue global_load_dwordx4 -> VGPR for kstep k+1 (no wait),
// ds_read + MFMA on kstep k from LDS buf[k&1], then ds_write the prefetched
// regs to buf[k+1 & 1] (compiler places the vmcnt wait HERE, after compute —
// ~32KB/block stays in flight during the MFMA phase), one __syncthreads.
// Write-buffer != read-buffer, so a single barrier per kstep suffices.
// ---------------------------------------------------------------------------
__device__ __forceinline__ void gemm_core_pf(
    const ushort_t* __restrict__ A, int lda,
    const ushort_t* __restrict__ B, int ldb,
    int K, int tile_m, int tile_n,
    ushort_t* As, ushort_t* Bs,   // each 2 * 4096 ushorts (two 8KB buffers)
    floatx4 (&acc)[4][4]) {

    const int tid  = threadIdx.x;
    const int lane = tid & 63;
    const int wave = tid >> 6;
    const int wm   = wave >> 1, wn = wave & 1;
    const int quad = lane >> 4;
    const int l16  = lane & 15;

#pragma unroll
    for (int i = 0; i < 4; i++)
#pragma unroll
        for (int j = 0; j < 4; j++) acc[i][j] = (floatx4){0.f, 0.f, 0.f, 0.f};

    // two 16B segments per thread per matrix (512 segs per 128x32 tile)
    const int s0 = tid, s1 = tid + 256;
    const int r0 = s0 >> 2, c0 = (s0 ^ r0 ^ (r0 >> 2)) & 3;
    const int r1 = s1 >> 2, c1 = (s1 ^ r1 ^ (r1 >> 2)) & 3;
    const ushort_t* ga0 = A + (long)(r0 + tile_m) * lda + c0 * 8;
    const ushort_t* ga1 = A + (long)(r1 + tile_m) * lda + c1 * 8;
    const ushort_t* gb0 = B + (long)(r0 + tile_n) * ldb + c0 * 8;
    const ushort_t* gb1 = B + (long)(r1 + tile_n) * ldb + c1 * 8;

    const int nk = K >> 5;

    // prologue: stage kstep 0 through VGPRs into buf 0
    bf16x8 ra0 = *(const bf16x8*)ga0;
    bf16x8 ra1 = *(const bf16x8*)ga1;
    bf16x8 rb0 = *(const bf16x8*)gb0;
    bf16x8 rb1 = *(const bf16x8*)gb1;
    *(bf16x8*)&As[s0 * 8] = ra0;
    *(bf16x8*)&As[s1 * 8] = ra1;
    *(bf16x8*)&Bs[s0 * 8] = rb0;
    *(bf16x8*)&Bs[s1 * 8] = rb1;
    __syncthreads();

    for (int ks = 0; ks < nk; ++ks) {
        const int cur = ks & 1, nxt = cur ^ 1;

        // prefetch kstep ks+1 into VGPRs (independent of LDS/barrier)
        if (ks + 1 < nk) {
            const int k1 = (ks + 1) << 5;
            ra0 = *(const bf16x8*)(ga0 + k1);
            ra1 = *(const bf16x8*)(ga1 + k1);
            rb0 = *(const bf16x8*)(gb0 + k1);
            rb1 = *(const bf16x8*)(gb1 + k1);
        }

        const ushort_t* as = &As[cur * 4096];
        const ushort_t* bs = &Bs[cur * 4096];
        bf16x8 af[4], bfr[4];
#pragma unroll
        for (int im = 0; im < 4; im++)
            af[im] = *(const bf16x8*)&as[sw(wm * 64 + im * 16 + l16, quad)];
#pragma unroll
        for (int in = 0; in < 4; in++)
            bfr[in] = *(const bf16x8*)&bs[sw(wn * 64 + in * 16 + l16, quad)];
#pragma unroll
        for (int im = 0; im < 4; im++)
#pragma unroll
            for (int in = 0; in < 4; in++)
                acc[im][in] = __builtin_amdgcn_mfma_f32_16x16x32_bf16(
                    af[im], bfr[in], acc[im][in], 0, 0, 0);

        if (ks + 1 < nk) {
            // vmcnt wait for the prefetch lands here, after the MFMA phase
            *(bf16x8*)&As[nxt * 4096 + s0 * 8] = ra0;
            *(bf16x8*)&As[nxt * 4096 + s1 * 8] = ra1;
            *(bf16x8*)&Bs[nxt * 4096 + s0 * 8] = rb0;
            *(bf16x8*)&Bs[nxt * 4096 + s1 * 8] = rb1;
            __syncthreads();  // publish buf[nxt]; also fences cur's reads
        }
    }
}

// ---------------------------------------------------------------------------
// fp32 -> bf16 conversion for x, W_q, W_k, W_v ; trailing blocks zero lsum
// ---------------------------------------------------------------------------
__global__ void cvt_kernel(const float* __restrict__ x,
                           const float* __restrict__ wq,
                           const float* __restrict__ wk,
                           const float* __restrict__ wv,
                           ushort_t* __restrict__ dst,
                           float* __restrict__ lsum) {
    if (blockIdx.x >= 11264) {
        int idx = (blockIdx.x - 11264) * 256 + threadIdx.x;  // [0,2048)
        ((float4*)lsum)[idx] = (float4){0.f, 0.f, 0.f, 0.f};
        return;
    }
    const long NX = 8388608, NW = 1048576;
    long g = ((long)blockIdx.x * blockDim.x + threadIdx.x) * 4;
    const float* src;
    long off;
    if (g < NX)             { src = x;  off = g; }
    else if (g < NX + NW)   { src = wq; off = g - NX; }
    else if (g < NX + 2*NW) { src = wk; off = g - NX - NW; }
    else                    { src = wv; off = g - NX - 2*NW; }
    float4 v = *(const float4*)(src + off);
    ushort4 o;
    o.x = f2bf(v.x); o.y = f2bf(v.y); o.z = f2bf(v.z); o.w = f2bf(v.w);
    *(ushort4*)(dst + g) = o;
}

// ---------------------------------------------------------------------------
// Fused projections: z=0 -> Q = x Wq^T, z=1 -> K = x Wk^T, z=2 -> V^T = Wv x^T
// ---------------------------------------------------------------------------
__global__ __launch_bounds__(256) void qkv_kernel(
    const ushort_t* __restrict__ xb,
    const ushort_t* __restrict__ wqb,
    const ushort_t* __restrict__ wkb,
    const ushort_t* __restrict__ wvb,
    ushort_t* __restrict__ Qb,
    ushort_t* __restrict__ Kb,
    ushort_t* __restrict__ VTb) {

    __shared__ __align__(16) ushort_t As[2 * 128 * 32];
    __shared__ __align__(16) ushort_t Bs[2 * 128 * 32];

    const int z = blockIdx.z;
    const ushort_t *A, *B;
    ushort_t* C;
    int ldc, tile_m, tile_n;
    if (z == 2) {  // V^T = Wv x^T : M=1024 (x), N=8192 (y)
        A = wvb; B = xb; C = VTb; ldc = 8192;
        tile_m = blockIdx.x * 128; tile_n = blockIdx.y * 128;
    } else {       // Q/K = x W^T : M=8192 (y), N=1024 (x)
        A = xb; B = z ? wkb : wqb; C = z ? Kb : Qb; ldc = 1024;
        tile_m = blockIdx.y * 128; tile_n = blockIdx.x * 128;
    }

    floatx4 acc[4][4];
    gemm_core_pf(A, 1024, B, 1024, 1024, tile_m, tile_n, As, Bs, acc);

    const int lane = threadIdx.x & 63, wave = threadIdx.x >> 6;
    const int wm = wave >> 1, wn = wave & 1, quad = lane >> 4, l16 = lane & 15;
#pragma unroll
    for (int im = 0; im < 4; im++)
#pragma unroll
        for (int r = 0; r < 4; r++) {
            int row = tile_m + wm * 64 + im * 16 + quad * 4 + r;
#pragma unroll
            for (int in = 0; in < 4; in++) {
                int col = tile_n + wn * 64 + in * 16 + l16;
                C[(long)row * ldc + col] = f2bf(acc[im][in][r]);
            }
        }
}

// ---------------------------------------------------------------------------
// P = exp(scale * Q K^T) per batch + fused row-sum atomics into lsum
// ---------------------------------------------------------------------------
__global__ __launch_bounds__(256) void pexp_kernel(
    const ushort_t* __restrict__ Qb,
    const ushort_t* __restrict__ Kb,
    ushort_t* __restrict__ Pb,
    float* __restrict__ lsum) {

    __shared__ __align__(16) ushort_t As[2 * 128 * 32];
    __shared__ __align__(16) ushort_t Bs[2 * 128 * 32];

    const int z = blockIdx.z;
    const ushort_t* A = Qb + (long)z * 2097152;
    const ushort_t* B = Kb + (long)z * 2097152;
    ushort_t* C = Pb + (long)z * 4194304;
    float* l = lsum + z * 2048;
    const int tile_m = blockIdx.y * 128;
    const int tile_n = blockIdx.x * 128;

    floatx4 acc[4][4];
    gemm_core_pf(A, 1024, B, 1024, 1024, tile_m, tile_n, As, Bs, acc);

    const float scale = 0.022097086912079608f;  // 1/sqrt(2048)
    const int lane = threadIdx.x & 63, wave = threadIdx.x >> 6;
    const int wm = wave >> 1, wn = wave & 1, quad = lane >> 4, l16 = lane & 15;
#pragma unroll
    for (int im = 0; im < 4; im++)
#pragma unroll
        for (int r = 0; r < 4; r++) {
            int row = tile_m + wm * 64 + im * 16 + quad * 4 + r;
            float psum = 0.f;
#pragma unroll
            for (int in = 0; in < 4; in++) {
                int col = tile_n + wn * 64 + in * 16 + l16;
                float e = __expf(acc[im][in][r] * scale);
                C[(long)row * 2048 + col] = f2bf(e);
                psum += e;
            }
            psum += __shfl_xor(psum, 1, 64);
            psum += __shfl_xor(psum, 2, 64);
            psum += __shfl_xor(psum, 4, 64);
            psum += __shfl_xor(psum, 8, 64);
            if (l16 == 0) atomicAdd(&l[row], psum);
        }
}

// ---------------------------------------------------------------------------
// out = (P V) / l per batch
// ---------------------------------------------------------------------------
__global__ __launch_bounds__(256) void out_kernel(
    const ushort_t* __restrict__ Pb,
    const ushort_t* __restrict__ VTb,
    float* __restrict__ out,
    const float* __restrict__ lsum) {

    __shared__ __align__(16) ushort_t As[2 * 128 * 32];
    __shared__ __align__(16) ushort_t Bs[2 * 128 * 32];

    const int z = blockIdx.z;
    const ushort_t* A = Pb + (long)z * 4194304;   // [2048][2048]
    const ushort_t* B = VTb + (long)z * 2048;     // ldb=8192, batch col slice
    float* C = out + (long)z * 2097152;
    const float* l = lsum + z * 2048;
    const int tile_m = blockIdx.y * 128;
    const int tile_n = blockIdx.x * 128;

    floatx4 acc[4][4];
    gemm_core_pf(A, 2048, B, 8192, 2048, tile_m, tile_n, As, Bs, acc);

    const int lane = threadIdx.x & 63, wave = threadIdx.x >> 6;
    const int wm = wave >> 1, wn = wave & 1, quad = lane >> 4, l16 = lane & 15;
#pragma unroll
    for (int im = 0; im < 4; im++)
#pragma unroll
        for (int r = 0; r < 4; r++) {
            int row = tile_m + wm * 64 + im * 16 + quad * 4 + r;
            float li = 1.0f / l[row];
#pragma unroll
            for (int in = 0; in < 4; in++) {
                int col = tile_n + wn * 64 + in * 16 + l16;
                C[(long)row * 1024 + col] = acc[im][in][r] * li;
            }
        }
}

// ---------------------------------------------------------------------------
extern "C" void kernel_launch(void* const* d_in, const int* in_sizes, int n_in,
                              void* d_out, int out_size, void* d_ws, size_t ws_size,
                              hipStream_t stream) {
    const float* x  = (const float*)d_in[0];
    const float* wq = (const float*)d_in[1];
    const float* wk = (const float*)d_in[2];
    const float* wv = (const float*)d_in[3];

    ushort_t* xb  = (ushort_t*)d_ws;          // [8192,1024] bf16
    ushort_t* wqb = xb  + 8388608;            // [1024,1024]
    ushort_t* wkb = wqb + 1048576;
    ushort_t* wvb = wkb + 1048576;
    ushort_t* Qb  = wvb + 1048576;            // [8192,1024]
    ushort_t* Kb  = Qb  + 8388608;            // [8192,1024]
    ushort_t* VTb = Kb  + 8388608;            // [1024,8192]
    ushort_t* Pb  = VTb + 8388608;            // [4][2048][2048]
    float*    lsum = (float*)(Pb + 16777216); // [4][2048] fp32 row sums
    float*    out  = (float*)d_out;

    // 1) fp32->bf16 (+ zero lsum in trailing 8 blocks)
    cvt_kernel<<<11272, 256, 0, stream>>>(x, wq, wk, wv, xb, lsum);

    // 2) Q, K, V^T in one dispatch (1536 blocks)
    qkv_kernel<<<dim3(8, 64, 3), 256, 0, stream>>>(xb, wqb, wkb, wvb, Qb, Kb, VTb);

    // 3) P = exp(scale * Q K^T) + row sums (1024 blocks)
    pexp_kernel<<<dim3(16, 16, 4), 256, 0, stream>>>(Qb, Kb, Pb, lsum);

    // 4) out = (P V) / l (512 blocks)
    out_kernel<<<dim3(8, 16, 4), 256, 0, stream>>>(Pb, VTb, out, lsum);
}

// Round 7
// 269.828 us; speedup vs baseline: 1.4650x; 1.0101x over previous
//
#include <hip/hip_runtime.h>

typedef unsigned short ushort_t;
typedef __attribute__((ext_vector_type(8))) __bf16 bf16x8;
typedef __attribute__((ext_vector_type(4))) float floatx4;

__device__ __forceinline__ ushort_t f2bf(float f) {
    unsigned int u = __builtin_bit_cast(unsigned int, f);
    u = (u + 0x7fffu + ((u >> 16) & 1u)) >> 16;
    return (ushort_t)u;
}

// XOR-swizzled LDS offset (ushort index) of the 8-elem group (row, cg).
__device__ __forceinline__ int sw(int row, int cg) {
    return ((row << 2) + ((cg ^ row ^ (row >> 2)) & 3)) << 3;
}

// ---------------------------------------------------------------------------
// VGPR-prefetch double-buffered bf16 GEMM core (R6 transport, templated):
// BM x BN tile, 256 threads (4 waves 2x2), wave tile (IM*16)x(IN*16),
// BM = 32*IM, BN = 32*IN. Per kstep: global->VGPR prefetch of k+1, ds_read +
// MFMA on k, ds_write prefetch to the other buffer, one __syncthreads.
// ---------------------------------------------------------------------------
template <int BM, int BN, int IM, int IN>
__device__ __forceinline__ void gemm_core_pf(
    const ushort_t* __restrict__ A, int lda,
    const ushort_t* __restrict__ B, int ldb,
    int K, int tile_m, int tile_n,
    ushort_t* As, ushort_t* Bs,   // each 2 * BM*32 / 2 * BN*32 ushorts
    floatx4 (&acc)[IM][IN]) {

    constexpr int SA = BM * 4 / 256;  // 16B staging segs per thread (A)
    constexpr int SB = BN * 4 / 256;

    const int tid  = threadIdx.x;
    const int lane = tid & 63;
    const int wave = tid >> 6;
    const int wm   = wave >> 1, wn = wave & 1;
    const int quad = lane >> 4;
    const int l16  = lane & 15;

#pragma unroll
    for (int i = 0; i < IM; i++)
#pragma unroll
        for (int j = 0; j < IN; j++) acc[i][j] = (floatx4){0.f, 0.f, 0.f, 0.f};

    const ushort_t* ga[SA];
    int la[SA];
#pragma unroll
    for (int s = 0; s < SA; s++) {
        int seg = tid + s * 256;
        int r = seg >> 2, c = (seg ^ r ^ (r >> 2)) & 3;
        ga[s] = A + (long)(r + tile_m) * lda + c * 8;
        la[s] = seg * 8;
    }
    const ushort_t* gb[SB];
    int lb[SB];
#pragma unroll
    for (int s = 0; s < SB; s++) {
        int seg = tid + s * 256;
        int r = seg >> 2, c = (seg ^ r ^ (r >> 2)) & 3;
        gb[s] = B + (long)(r + tile_n) * ldb + c * 8;
        lb[s] = seg * 8;
    }

    const int nk = K >> 5;

    bf16x8 ra[SA], rb[SB];
#pragma unroll
    for (int s = 0; s < SA; s++) ra[s] = *(const bf16x8*)ga[s];
#pragma unroll
    for (int s = 0; s < SB; s++) rb[s] = *(const bf16x8*)gb[s];
#pragma unroll
    for (int s = 0; s < SA; s++) *(bf16x8*)&As[la[s]] = ra[s];
#pragma unroll
    for (int s = 0; s < SB; s++) *(bf16x8*)&Bs[lb[s]] = rb[s];
    __syncthreads();

    for (int ks = 0; ks < nk; ++ks) {
        const int cur = ks & 1, nxt = cur ^ 1;

        if (ks + 1 < nk) {
            const int k1 = (ks + 1) << 5;
#pragma unroll
            for (int s = 0; s < SA; s++) ra[s] = *(const bf16x8*)(ga[s] + k1);
#pragma unroll
            for (int s = 0; s < SB; s++) rb[s] = *(const bf16x8*)(gb[s] + k1);
        }

        const ushort_t* as = &As[cur * BM * 32];
        const ushort_t* bs = &Bs[cur * BN * 32];
        bf16x8 af[IM], bfr[IN];
#pragma unroll
        for (int im = 0; im < IM; im++)
            af[im] = *(const bf16x8*)&as[sw(wm * IM * 16 + im * 16 + l16, quad)];
#pragma unroll
        for (int in = 0; in < IN; in++)
            bfr[in] = *(const bf16x8*)&bs[sw(wn * IN * 16 + in * 16 + l16, quad)];
#pragma unroll
        for (int im = 0; im < IM; im++)
#pragma unroll
            for (int in = 0; in < IN; in++)
                acc[im][in] = __builtin_amdgcn_mfma_f32_16x16x32_bf16(
                    af[im], bfr[in], acc[im][in], 0, 0, 0);

        if (ks + 1 < nk) {
#pragma unroll
            for (int s = 0; s < SA; s++) *(bf16x8*)&As[nxt * BM * 32 + la[s]] = ra[s];
#pragma unroll
            for (int s = 0; s < SB; s++) *(bf16x8*)&Bs[nxt * BN * 32 + lb[s]] = rb[s];
            __syncthreads();
        }
    }
}

// ---------------------------------------------------------------------------
// fp32 -> bf16 conversion for x and W_v ; trailing blocks zero lsum
// ---------------------------------------------------------------------------
__global__ void cvt_kernel(const float* __restrict__ x,
                           const float* __restrict__ wv,
                           ushort_t* __restrict__ xb,
                           ushort_t* __restrict__ wvb,
                           float* __restrict__ lsum) {
    const int bx = blockIdx.x;
    if (bx >= 9216) {
        int idx = (bx - 9216) * 256 + threadIdx.x;  // [0,2048)
        ((float4*)lsum)[idx] = (float4){0.f, 0.f, 0.f, 0.f};
        return;
    }
    const float* src;
    ushort_t* dst;
    long g;
    if (bx < 8192) { src = x;  dst = xb;  g = ((long)bx * 256 + threadIdx.x) * 4; }
    else           { src = wv; dst = wvb; g = ((long)(bx - 8192) * 256 + threadIdx.x) * 4; }
    float4 v = *(const float4*)(src + g);
    ushort4 o;
    o.x = f2bf(v.x); o.y = f2bf(v.y); o.z = f2bf(v.z); o.w = f2bf(v.w);
    *(ushort4*)(dst + g) = o;
}

// ---------------------------------------------------------------------------
// Transpose + cast: W (fp32 [1024][1024], [h][d]) -> W^T (bf16 [d][h]).
// z=0: wq -> wqT ; z=1: wk -> wkT. 64x64 tiles via LDS.
// ---------------------------------------------------------------------------
__global__ void tkern(const float* __restrict__ wq, const float* __restrict__ wk,
                      ushort_t* __restrict__ wqT, ushort_t* __restrict__ wkT) {
    const float* src = blockIdx.z ? wk : wq;
    ushort_t* dst = blockIdx.z ? wkT : wqT;
    __shared__ ushort_t tile[64 * 80];

    const int t = threadIdx.x;
    const int h0 = blockIdx.y * 64, d0 = blockIdx.x * 64;
    {
        int i = t >> 2, cg = (t & 3) << 4;   // local row, col group of 16
        const float4* p = (const float4*)(src + (long)(h0 + i) * 1024 + d0 + cg);
#pragma unroll
        for (int k = 0; k < 4; k++) {
            float4 v = p[k];
            ushort_t* q = &tile[i * 80 + cg + k * 4];
            q[0] = f2bf(v.x); q[1] = f2bf(v.y); q[2] = f2bf(v.z); q[3] = f2bf(v.w);
        }
    }
    __syncthreads();
    {
        int j = t >> 2, ig = (t & 3) << 4;   // out row (=d), h group of 16
        ushort_t tmp[16];
#pragma unroll
        for (int k = 0; k < 16; k++) tmp[k] = tile[(ig + k) * 80 + j];
        ushort_t* o = dst + (long)(d0 + j) * 1024 + h0 + ig;
        *(uint4*)o = ((uint4*)tmp)[0];
        *(uint4*)(o + 8) = ((uint4*)tmp)[1];
    }
}

// ---------------------------------------------------------------------------
// G[e][d] = sum_h Wk[h][e] * Wq[h][d]  (= gemm_bt(A=wkT, B=wqT), 64x64 tiles)
// ---------------------------------------------------------------------------
__global__ __launch_bounds__(256) void ggemm_kernel(
    const ushort_t* __restrict__ wkT, const ushort_t* __restrict__ wqT,
    ushort_t* __restrict__ G) {
    __shared__ __align__(16) ushort_t As[2 * 64 * 32];
    __shared__ __align__(16) ushort_t Bs[2 * 64 * 32];
    const int tile_m = blockIdx.y * 64, tile_n = blockIdx.x * 64;
    floatx4 acc[2][2];
    gemm_core_pf<64, 64, 2, 2>(wkT, 1024, wqT, 1024, 1024, tile_m, tile_n, As, Bs, acc);
    const int lane = threadIdx.x & 63, wave = threadIdx.x >> 6;
    const int wm = wave >> 1, wn = wave & 1, quad = lane >> 4, l16 = lane & 15;
#pragma unroll
    for (int im = 0; im < 2; im++)
#pragma unroll
        for (int r = 0; r < 4; r++) {
            int row = tile_m + wm * 32 + im * 16 + quad * 4 + r;
#pragma unroll
            for (int in = 0; in < 2; in++) {
                int col = tile_n + wn * 32 + in * 16 + l16;
                G[(long)row * 1024 + col] = f2bf(acc[im][in][r]);
            }
        }
}

// ---------------------------------------------------------------------------
// z=0: Y = x G^T (8192x1024, K=1024)  ;  z=1: V^T = Wv x^T (1024x8192)
// ---------------------------------------------------------------------------
__global__ __launch_bounds__(256) void yv_kernel(
    const ushort_t* __restrict__ xb,
    const ushort_t* __restrict__ Gb,
    const ushort_t* __restrict__ wvb,
    ushort_t* __restrict__ Yb,
    ushort_t* __restrict__ VTb) {

    __shared__ __align__(16) ushort_t As[2 * 128 * 32];
    __shared__ __align__(16) ushort_t Bs[2 * 128 * 32];

    const int z = blockIdx.z;
    const ushort_t *A, *B;
    ushort_t* C;
    int ldc, tile_m, tile_n;
    if (z == 0) {  // Y[q][e] = sum_d x[q][d] G[e][d]
        A = xb; B = Gb; C = Yb; ldc = 1024;
        tile_m = blockIdx.y * 128; tile_n = blockIdx.x * 128;
    } else {       // VT[h][s] = sum_d Wv[h][d] x[s][d]
        A = wvb; B = xb; C = VTb; ldc = 8192;
        tile_m = blockIdx.x * 128; tile_n = blockIdx.y * 128;
    }

    floatx4 acc[4][4];
    gemm_core_pf<128, 128, 4, 4>(A, 1024, B, 1024, 1024, tile_m, tile_n, As, Bs, acc);

    const int lane = threadIdx.x & 63, wave = threadIdx.x >> 6;
    const int wm = wave >> 1, wn = wave & 1, quad = lane >> 4, l16 = lane & 15;
#pragma unroll
    for (int im = 0; im < 4; im++)
#pragma unroll
        for (int r = 0; r < 4; r++) {
            int row = tile_m + wm * 64 + im * 16 + quad * 4 + r;
#pragma unroll
            for (int in = 0; in < 4; in++) {
                int col = tile_n + wn * 64 + in * 16 + l16;
                C[(long)row * ldc + col] = f2bf(acc[im][in][r]);
            }
        }
}

// ---------------------------------------------------------------------------
// P = exp(scale * Y x^T) per batch + fused row-sum atomics into lsum
// ---------------------------------------------------------------------------
__global__ __launch_bounds__(256) void pexp_kernel(
    const ushort_t* __restrict__ Yb,
    const ushort_t* __restrict__ xb,
    ushort_t* __restrict__ Pb,
    float* __restrict__ lsum) {

    __shared__ __align__(16) ushort_t As[2 * 128 * 32];
    __shared__ __align__(16) ushort_t Bs[2 * 128 * 32];

    const int z = blockIdx.z;
    const ushort_t* A = Yb + (long)z * 2097152;
    const ushort_t* B = xb + (long)z * 2097152;
    ushort_t* C = Pb + (long)z * 4194304;
    float* l = lsum + z * 2048;
    const int tile_m = blockIdx.y * 128;
    const int tile_n = blockIdx.x * 128;

    floatx4 acc[4][4];
    gemm_core_pf<128, 128, 4, 4>(A, 1024, B, 1024, 1024, tile_m, tile_n, As, Bs, acc);

    const float scale = 0.022097086912079608f;  // 1/sqrt(2048)
    const int lane = threadIdx.x & 63, wave = threadIdx.x >> 6;
    const int wm = wave >> 1, wn = wave & 1, quad = lane >> 4, l16 = lane & 15;
#pragma unroll
    for (int im = 0; im < 4; im++)
#pragma unroll
        for (int r = 0; r < 4; r++) {
            int row = tile_m + wm * 64 + im * 16 + quad * 4 + r;
            float psum = 0.f;
#pragma unroll
            for (int in = 0; in < 4; in++) {
                int col = tile_n + wn * 64 + in * 16 + l16;
                float e = __expf(acc[im][in][r] * scale);
                C[(long)row * 2048 + col] = f2bf(e);
                psum += e;
            }
            psum += __shfl_xor(psum, 1, 64);
            psum += __shfl_xor(psum, 2, 64);
            psum += __shfl_xor(psum, 4, 64);
            psum += __shfl_xor(psum, 8, 64);
            if (l16 == 0) atomicAdd(&l[row], psum);
        }
}

// ---------------------------------------------------------------------------
// out = (P V) / l per batch
// ---------------------------------------------------------------------------
__global__ __launch_bounds__(256) void out_kernel(
    const ushort_t* __restrict__ Pb,
    const ushort_t* __restrict__ VTb,
    float* __restrict__ out,
    const float* __restrict__ lsum) {

    __shared__ __align__(16) ushort_t As[2 * 128 * 32];
    __shared__ __align__(16) ushort_t Bs[2 * 128 * 32];

    const int z = blockIdx.z;
    const ushort_t* A = Pb + (long)z * 4194304;   // [2048][2048]
    const ushort_t* B = VTb + (long)z * 2048;     // ldb=8192, batch col slice
    float* C = out + (long)z * 2097152;
    const float* l = lsum + z * 2048;
    const int tile_m = blockIdx.y * 128;
    const int tile_n = blockIdx.x * 128;

    floatx4 acc[4][4];
    gemm_core_pf<128, 128, 4, 4>(A, 2048, B, 8192, 2048, tile_m, tile_n, As, Bs, acc);

    const int lane = threadIdx.x & 63, wave = threadIdx.x >> 6;
    const int wm = wave >> 1, wn = wave & 1, quad = lane >> 4, l16 = lane & 15;
#pragma unroll
    for (int im = 0; im < 4; im++)
#pragma unroll
        for (int r = 0; r < 4; r++) {
            int row = tile_m + wm * 64 + im * 16 + quad * 4 + r;
            float li = 1.0f / l[row];
#pragma unroll
            for (int in = 0; in < 4; in++) {
                int col = tile_n + wn * 64 + in * 16 + l16;
                C[(long)row * 1024 + col] = acc[im][in][r] * li;
            }
        }
}

// ---------------------------------------------------------------------------
extern "C" void kernel_launch(void* const* d_in, const int* in_sizes, int n_in,
                              void* d_out, int out_size, void* d_ws, size_t ws_size,
                              hipStream_t stream) {
    const float* x  = (const float*)d_in[0];
    const float* wq = (const float*)d_in[1];
    const float* wk = (const float*)d_in[2];
    const float* wv = (const float*)d_in[3];

    ushort_t* xb  = (ushort_t*)d_ws;          // [8192,1024] bf16
    ushort_t* wvb = xb  + 8388608;            // [1024,1024]
    ushort_t* wqT = wvb + 1048576;            // [1024,1024]  Wq^T bf16
    ushort_t* wkT = wqT + 1048576;            // [1024,1024]  Wk^T bf16
    ushort_t* Gb  = wkT + 1048576;            // [1024,1024]  G[e][d]
    ushort_t* Yb  = Gb  + 1048576;            // [8192,1024]  Y = x G^T
    ushort_t* VTb = Yb  + 8388608;            // [1024,8192]
    ushort_t* Pb  = VTb + 8388608;            // [4][2048][2048]
    float*    lsum = (float*)(Pb + 16777216); // [4][2048] fp32 row sums
    float*    out  = (float*)d_out;

    // 1) fp32->bf16 x, Wv (+ zero lsum)
    cvt_kernel<<<9224, 256, 0, stream>>>(x, wv, xb, wvb, lsum);

    // 2) Wq^T, Wk^T (transpose + cast)
    tkern<<<dim3(16, 16, 2), 256, 0, stream>>>(wq, wk, wqT, wkT);

    // 3) G = Wk^T-contract-Wq (G[e][d] = sum_h Wk[h][e] Wq[h][d])
    ggemm_kernel<<<dim3(16, 16), 256, 0, stream>>>(wkT, wqT, Gb);

    // 4) Y = x G^T and V^T = Wv x^T (1024 blocks)
    yv_kernel<<<dim3(8, 64, 2), 256, 0, stream>>>(xb, Gb, wvb, Yb, VTb);

    // 5) P = exp(scale * Y x^T) + row sums (1024 blocks)
    pexp_kernel<<<dim3(16, 16, 4), 256, 0, stream>>>(Yb, xb, Pb, lsum);

    // 6) out = (P V) / l (512 blocks)
    out_kernel<<<dim3(8, 16, 4), 256, 0, stream>>>(Pb, VTb, out, lsum);
}

// Round 9
// 243.924 us; speedup vs baseline: 1.6206x; 1.1062x over previous
//
#include <hip/hip_runtime.h>

typedef unsigned short ushort_t;
typedef __attribute__((ext_vector_type(8))) __bf16 bf16x8;
typedef __attribute__((ext_vector_type(4))) float floatx4;

__device__ __forceinline__ ushort_t f2bf(float f) {
    unsigned int u = __builtin_bit_cast(unsigned int, f);
    u = (u + 0x7fffu + ((u >> 16) & 1u)) >> 16;
    return (ushort_t)u;
}

__device__ __forceinline__ void async16(const ushort_t* g, ushort_t* l) {
    __builtin_amdgcn_global_load_lds(
        (const __attribute__((address_space(1))) unsigned int*)g,
        (__attribute__((address_space(3))) unsigned int*)l,
        16 /*bytes*/, 0 /*offset*/, 0 /*aux*/);
}

// XOR-swizzled LDS offset (ushort index) of the 8-elem group (row, cg).
__device__ __forceinline__ int sw(int row, int cg) {
    return ((row << 2) + ((cg ^ row ^ (row >> 2)) & 3)) << 3;
}

// ---------------------------------------------------------------------------
// Triple-buffered DMA-pipelined bf16 GEMM core (AITER-style K-loop).
// BM x BN tile, 256 threads (4 waves 2x2), wave tile (IM*16)x(IN*16).
// Per kstep k (ORDER MATTERS — fixes R8's cross-wave RAW race):
//   s_waitcnt vmcnt(NV)   each wave drains ITS OWN kstep-k loads
//                         (leaves kstep k+1's NV loads in flight)
//   s_barrier             => now ALL waves' kstep-k loads have landed, and
//                            all iter k-1 ds_reads are complete
//   issue global_load_lds for kstep k+2 into slot (k+2)%3  (== (k-1)%3,
//                            safe: its readers finished before the barrier)
//   ds_read slot k%3 ; MFMA
// vmcnt is per-wave: the wait MUST precede the barrier for other waves'
// DMA writes to be visible. Loads get ~2 full kstep-walls of latency cover.
// ---------------------------------------------------------------------------
template <int BM, int BN, int IM, int IN>
__device__ __forceinline__ void gemm_core_p3(
    const ushort_t* __restrict__ A, int lda,
    const ushort_t* __restrict__ B, int ldb,
    int K, int tile_m, int tile_n,
    ushort_t* buf,                    // 3 * (BM+BN)*32 ushorts
    floatx4 (&acc)[IM][IN]) {

    constexpr int SA = BM * 4 / 256;      // 16B DMA instrs per kstep (A)
    constexpr int SB = BN * 4 / 256;
    constexpr int SLOT = (BM + BN) * 32;  // ushorts per slot
    constexpr int BOFF = BM * 32;         // B region offset within slot

    const int tid  = threadIdx.x;
    const int lane = tid & 63;
    const int wave = tid >> 6;
    const int wm   = wave >> 1, wn = wave & 1;
    const int quad = lane >> 4;
    const int l16  = lane & 15;

#pragma unroll
    for (int i = 0; i < IM; i++)
#pragma unroll
        for (int j = 0; j < IN; j++) acc[i][j] = (floatx4){0.f, 0.f, 0.f, 0.f};

    const ushort_t* ga[SA];
    int la[SA];
#pragma unroll
    for (int s = 0; s < SA; s++) {
        int seg = tid + s * 256;
        int r = seg >> 2, c = (seg ^ r ^ (r >> 2)) & 3;
        ga[s] = A + (long)(r + tile_m) * lda + c * 8;
        la[s] = seg * 8;
    }
    const ushort_t* gb[SB];
    int lb[SB];
#pragma unroll
    for (int s = 0; s < SB; s++) {
        int seg = tid + s * 256;
        int r = seg >> 2, c = (seg ^ r ^ (r >> 2)) & 3;
        gb[s] = B + (long)(r + tile_n) * ldb + c * 8;
        lb[s] = BOFF + seg * 8;
    }

    const int nk = K >> 5;

    // prologue: issue ksteps 0 and 1 into slots 0 and 1
#pragma unroll
    for (int p = 0; p < 2; ++p) {
#pragma unroll
        for (int s = 0; s < SA; s++) async16(ga[s] + p * 32, buf + p * SLOT + la[s]);
#pragma unroll
        for (int s = 0; s < SB; s++) async16(gb[s] + p * 32, buf + p * SLOT + lb[s]);
    }

    int slot = 0, slot2 = 2;
    for (int k = 0; k < nk; ++k) {
        // drain my kstep-k loads (leave kstep k+1 in flight), THEN barrier
        if (k + 1 < nk) {
            if constexpr (SA + SB == 4)
                asm volatile("s_waitcnt vmcnt(4)" ::: "memory");
            else
                asm volatile("s_waitcnt vmcnt(2)" ::: "memory");
        } else {
            asm volatile("s_waitcnt vmcnt(0)" ::: "memory");
        }
        __builtin_amdgcn_s_barrier();
        asm volatile("" ::: "memory");

        if (k + 2 < nk) {
            const int koff = (k + 2) << 5;
            ushort_t* dst = buf + slot2 * SLOT;
#pragma unroll
            for (int s = 0; s < SA; s++) async16(ga[s] + koff, dst + la[s]);
#pragma unroll
            for (int s = 0; s < SB; s++) async16(gb[s] + koff, dst + lb[s]);
        }

        const ushort_t* as = buf + slot * SLOT;
        const ushort_t* bs = as + BOFF;
        bf16x8 af[IM], bfr[IN];
#pragma unroll
        for (int im = 0; im < IM; im++)
            af[im] = *(const bf16x8*)&as[sw(wm * IM * 16 + im * 16 + l16, quad)];
#pragma unroll
        for (int in = 0; in < IN; in++)
            bfr[in] = *(const bf16x8*)&bs[sw(wn * IN * 16 + in * 16 + l16, quad)];
#pragma unroll
        for (int im = 0; im < IM; im++)
#pragma unroll
            for (int in = 0; in < IN; in++)
                acc[im][in] = __builtin_amdgcn_mfma_f32_16x16x32_bf16(
                    af[im], bfr[in], acc[im][in], 0, 0, 0);

        slot  = (slot == 2) ? 0 : slot + 1;
        slot2 = (slot2 == 2) ? 0 : slot2 + 1;
    }
}

// ---------------------------------------------------------------------------
// fp32 -> bf16 conversion for x and W_v ; trailing blocks zero lsum
// ---------------------------------------------------------------------------
__global__ void cvt_kernel(const float* __restrict__ x,
                           const float* __restrict__ wv,
                           ushort_t* __restrict__ xb,
                           ushort_t* __restrict__ wvb,
                           float* __restrict__ lsum) {
    const int bx = blockIdx.x;
    if (bx >= 9216) {
        int idx = (bx - 9216) * 256 + threadIdx.x;  // [0,2048)
        ((float4*)lsum)[idx] = (float4){0.f, 0.f, 0.f, 0.f};
        return;
    }
    const float* src;
    ushort_t* dst;
    long g;
    if (bx < 8192) { src = x;  dst = xb;  g = ((long)bx * 256 + threadIdx.x) * 4; }
    else           { src = wv; dst = wvb; g = ((long)(bx - 8192) * 256 + threadIdx.x) * 4; }
    float4 v = *(const float4*)(src + g);
    ushort4 o;
    o.x = f2bf(v.x); o.y = f2bf(v.y); o.z = f2bf(v.z); o.w = f2bf(v.w);
    *(ushort4*)(dst + g) = o;
}

// ---------------------------------------------------------------------------
// Transpose + cast: W (fp32 [1024][1024], [h][d]) -> W^T (bf16 [d][h]).
// z=0: wq -> wqT ; z=1: wk -> wkT. 64x64 tiles via LDS.
// ---------------------------------------------------------------------------
__global__ void tkern(const float* __restrict__ wq, const float* __restrict__ wk,
                      ushort_t* __restrict__ wqT, ushort_t* __restrict__ wkT) {
    const float* src = blockIdx.z ? wk : wq;
    ushort_t* dst = blockIdx.z ? wkT : wqT;
    __shared__ ushort_t tile[64 * 80];

    const int t = threadIdx.x;
    const int h0 = blockIdx.y * 64, d0 = blockIdx.x * 64;
    {
        int i = t >> 2, cg = (t & 3) << 4;
        const float4* p = (const float4*)(src + (long)(h0 + i) * 1024 + d0 + cg);
#pragma unroll
        for (int k = 0; k < 4; k++) {
            float4 v = p[k];
            ushort_t* q = &tile[i * 80 + cg + k * 4];
            q[0] = f2bf(v.x); q[1] = f2bf(v.y); q[2] = f2bf(v.z); q[3] = f2bf(v.w);
        }
    }
    __syncthreads();
    {
        int j = t >> 2, ig = (t & 3) << 4;
        ushort_t tmp[16];
#pragma unroll
        for (int k = 0; k < 16; k++) tmp[k] = tile[(ig + k) * 80 + j];
        ushort_t* o = dst + (long)(d0 + j) * 1024 + h0 + ig;
        *(uint4*)o = ((uint4*)tmp)[0];
        *(uint4*)(o + 8) = ((uint4*)tmp)[1];
    }
}

// ---------------------------------------------------------------------------
// G[e][d] = sum_h Wk[h][e] * Wq[h][d]  (64x64 tiles)
// ---------------------------------------------------------------------------
__global__ __launch_bounds__(256) void ggemm_kernel(
    const ushort_t* __restrict__ wkT, const ushort_t* __restrict__ wqT,
    ushort_t* __restrict__ G) {
    __shared__ __align__(16) ushort_t buf[3 * 128 * 32];
    const int tile_m = blockIdx.y * 64, tile_n = blockIdx.x * 64;
    floatx4 acc[2][2];
    gemm_core_p3<64, 64, 2, 2>(wkT, 1024, wqT, 1024, 1024, tile_m, tile_n, buf, acc);
    const int lane = threadIdx.x & 63, wave = threadIdx.x >> 6;
    const int wm = wave >> 1, wn = wave & 1, quad = lane >> 4, l16 = lane & 15;
#pragma unroll
    for (int im = 0; im < 2; im++)
#pragma unroll
        for (int r = 0; r < 4; r++) {
            int row = tile_m + wm * 32 + im * 16 + quad * 4 + r;
#pragma unroll
            for (int in = 0; in < 2; in++) {
                int col = tile_n + wn * 32 + in * 16 + l16;
                G[(long)row * 1024 + col] = f2bf(acc[im][in][r]);
            }
        }
}

// ---------------------------------------------------------------------------
// z=0: Y = x G^T (8192x1024, K=1024)  ;  z=1: V^T = Wv x^T (1024x8192)
// ---------------------------------------------------------------------------
__global__ __launch_bounds__(256) void yv_kernel(
    const ushort_t* __restrict__ xb,
    const ushort_t* __restrict__ Gb,
    const ushort_t* __restrict__ wvb,
    ushort_t* __restrict__ Yb,
    ushort_t* __restrict__ VTb) {

    __shared__ __align__(16) ushort_t buf[3 * 256 * 32];

    const int z = blockIdx.z;
    const ushort_t *A, *B;
    ushort_t* C;
    int ldc, tile_m, tile_n;
    if (z == 0) {  // Y[q][e] = sum_d x[q][d] G[e][d]
        A = xb; B = Gb; C = Yb; ldc = 1024;
        tile_m = blockIdx.y * 128; tile_n = blockIdx.x * 128;
    } else {       // VT[h][s] = sum_d Wv[h][d] x[s][d]
        A = wvb; B = xb; C = VTb; ldc = 8192;
        tile_m = blockIdx.x * 128; tile_n = blockIdx.y * 128;
    }

    floatx4 acc[4][4];
    gemm_core_p3<128, 128, 4, 4>(A, 1024, B, 1024, 1024, tile_m, tile_n, buf, acc);

    const int lane = threadIdx.x & 63, wave = threadIdx.x >> 6;
    const int wm = wave >> 1, wn = wave & 1, quad = lane >> 4, l16 = lane & 15;
#pragma unroll
    for (int im = 0; im < 4; im++)
#pragma unroll
        for (int r = 0; r < 4; r++) {
            int row = tile_m + wm * 64 + im * 16 + quad * 4 + r;
#pragma unroll
            for (int in = 0; in < 4; in++) {
                int col = tile_n + wn * 64 + in * 16 + l16;
                C[(long)row * ldc + col] = f2bf(acc[im][in][r]);
            }
        }
}

// ---------------------------------------------------------------------------
// P = exp(scale * Y x^T) per batch + fused row-sum atomics into lsum
// ---------------------------------------------------------------------------
__global__ __launch_bounds__(256) void pexp_kernel(
    const ushort_t* __restrict__ Yb,
    const ushort_t* __restrict__ xb,
    ushort_t* __restrict__ Pb,
    float* __restrict__ lsum) {

    __shared__ __align__(16) ushort_t buf[3 * 256 * 32];

    const int z = blockIdx.z;
    const ushort_t* A = Yb + (long)z * 2097152;
    const ushort_t* B = xb + (long)z * 2097152;
    ushort_t* C = Pb + (long)z * 4194304;
    float* l = lsum + z * 2048;
    const int tile_m = blockIdx.y * 128;
    const int tile_n = blockIdx.x * 128;

    floatx4 acc[4][4];
    gemm_core_p3<128, 128, 4, 4>(A, 1024, B, 1024, 1024, tile_m, tile_n, buf, acc);

    const float scale = 0.022097086912079608f;  // 1/sqrt(2048)
    const int lane = threadIdx.x & 63, wave = threadIdx.x >> 6;
    const int wm = wave >> 1, wn = wave & 1, quad = lane >> 4, l16 = lane & 15;
#pragma unroll
    for (int im = 0; im < 4; im++)
#pragma unroll
        for (int r = 0; r < 4; r++) {
            int row = tile_m + wm * 64 + im * 16 + quad * 4 + r;
            float psum = 0.f;
#pragma unroll
            for (int in = 0; in < 4; in++) {
                int col = tile_n + wn * 64 + in * 16 + l16;
                float e = __expf(acc[im][in][r] * scale);
                C[(long)row * 2048 + col] = f2bf(e);
                psum += e;
            }
            psum += __shfl_xor(psum, 1, 64);
            psum += __shfl_xor(psum, 2, 64);
            psum += __shfl_xor(psum, 4, 64);
            psum += __shfl_xor(psum, 8, 64);
            if (l16 == 0) atomicAdd(&l[row], psum);
        }
}

// ---------------------------------------------------------------------------
// out = (P V) / l per batch
// ---------------------------------------------------------------------------
__global__ __launch_bounds__(256) void out_kernel(
    const ushort_t* __restrict__ Pb,
    const ushort_t* __restrict__ VTb,
    float* __restrict__ out,
    const float* __restrict__ lsum) {

    __shared__ __align__(16) ushort_t buf[3 * 256 * 32];

    const int z = blockIdx.z;
    const ushort_t* A = Pb + (long)z * 4194304;   // [2048][2048]
    const ushort_t* B = VTb + (long)z * 2048;     // ldb=8192, batch col slice
    float* C = out + (long)z * 2097152;
    const float* l = lsum + z * 2048;
    const int tile_m = blockIdx.y * 128;
    const int tile_n = blockIdx.x * 128;

    floatx4 acc[4][4];
    gemm_core_p3<128, 128, 4, 4>(A, 2048, B, 8192, 2048, tile_m, tile_n, buf, acc);

    const int lane = threadIdx.x & 63, wave = threadIdx.x >> 6;
    const int wm = wave >> 1, wn = wave & 1, quad = lane >> 4, l16 = lane & 15;
#pragma unroll
    for (int im = 0; im < 4; im++)
#pragma unroll
        for (int r = 0; r < 4; r++) {
            int row = tile_m + wm * 64 + im * 16 + quad * 4 + r;
            float li = 1.0f / l[row];
#pragma unroll
            for (int in = 0; in < 4; in++) {
                int col = tile_n + wn * 64 + in * 16 + l16;
                C[(long)row * 1024 + col] = acc[im][in][r] * li;
            }
        }
}

// ---------------------------------------------------------------------------
extern "C" void kernel_launch(void* const* d_in, const int* in_sizes, int n_in,
                              void* d_out, int out_size, void* d_ws, size_t ws_size,
                              hipStream_t stream) {
    const float* x  = (const float*)d_in[0];
    const float* wq = (const float*)d_in[1];
    const float* wk = (const float*)d_in[2];
    const float* wv = (const float*)d_in[3];

    ushort_t* xb  = (ushort_t*)d_ws;          // [8192,1024] bf16
    ushort_t* wvb = xb  + 8388608;            // [1024,1024]
    ushort_t* wqT = wvb + 1048576;            // [1024,1024]  Wq^T bf16
    ushort_t* wkT = wqT + 1048576;            // [1024,1024]  Wk^T bf16
    ushort_t* Gb  = wkT + 1048576;            // [1024,1024]  G[e][d]
    ushort_t* Yb  = Gb  + 1048576;            // [8192,1024]  Y = x G^T
    ushort_t* VTb = Yb  + 8388608;            // [1024,8192]
    ushort_t* Pb  = VTb + 8388608;            // [4][2048][2048]
    float*    lsum = (float*)(Pb + 16777216); // [4][2048] fp32 row sums
    float*    out  = (float*)d_out;

    // 1) fp32->bf16 x, Wv (+ zero lsum)
    cvt_kernel<<<9224, 256, 0, stream>>>(x, wv, xb, wvb, lsum);

    // 2) Wq^T, Wk^T (transpose + cast)
    tkern<<<dim3(16, 16, 2), 256, 0, stream>>>(wq, wk, wqT, wkT);

    // 3) G = Wk^T-contract-Wq
    ggemm_kernel<<<dim3(16, 16), 256, 0, stream>>>(wkT, wqT, Gb);

    // 4) Y = x G^T and V^T = Wv x^T (1024 blocks)
    yv_kernel<<<dim3(8, 64, 2), 256, 0, stream>>>(xb, Gb, wvb, Yb, VTb);

    // 5) P = exp(scale * Y x^T) + row sums (1024 blocks)
    pexp_kernel<<<dim3(16, 16, 4), 256, 0, stream>>>(Yb, xb, Pb, lsum);

    // 6) out = (P V) / l (512 blocks)
    out_kernel<<<dim3(8, 16, 4), 256, 0, stream>>>(Pb, VTb, out, lsum);
}

// Round 10
// 238.089 us; speedup vs baseline: 1.6603x; 1.0245x over previous
//
#include <hip/hip_runtime.h>

typedef unsigned short ushort_t;
typedef __attribute__((ext_vector_type(8))) __bf16 bf16x8;
typedef __attribute__((ext_vector_type(4))) float floatx4;

__device__ __forceinline__ ushort_t f2bf(float f) {
    unsigned int u = __builtin_bit_cast(unsigned int, f);
    u = (u + 0x7fffu + ((u >> 16) & 1u)) >> 16;
    return (ushort_t)u;
}

__device__ __forceinline__ void async16(const ushort_t* g, ushort_t* l) {
    __builtin_amdgcn_global_load_lds(
        (const __attribute__((address_space(1))) unsigned int*)g,
        (__attribute__((address_space(3))) unsigned int*)l,
        16 /*bytes*/, 0 /*offset*/, 0 /*aux*/);
}

// XOR-swizzled LDS offset (ushort index) of the 8-elem group (row, cg).
__device__ __forceinline__ int sw(int row, int cg) {
    return ((row << 2) + ((cg ^ row ^ (row >> 2)) & 3)) << 3;
}

// ---------------------------------------------------------------------------
// Triple-buffered DMA-pipelined bf16 GEMM core (R9-verified K-loop order),
// templated on wave count. NW waves in (NW/2) x 2 grid, wave tile 64x64
// (IM=IN=4, mfma_16x16x32). BM = NW*32 rows, BN = 128.
// Per kstep k:  s_waitcnt vmcnt(SA+SB)  (drain own kstep-k loads, keep k+1)
//               s_barrier               (all waves' k-loads now in LDS)
//               issue DMA for k+2 into slot (k+2)%3 (== (k-1)%3, readers done)
//               ds_read slot k%3 ; MFMA
// ---------------------------------------------------------------------------
template <int BM, int BN, int IM, int IN, int NW>
__device__ __forceinline__ void gemm_core_p3(
    const ushort_t* __restrict__ A, int lda,
    const ushort_t* __restrict__ B, int ldb,
    int K, int tile_m, int tile_n,
    ushort_t* buf,                    // 3 * (BM+BN)*32 ushorts
    floatx4 (&acc)[IM][IN]) {

    constexpr int NT = NW * 64;
    constexpr int SA = BM * 4 / NT;       // 16B DMA instrs per kstep (A)
    constexpr int SB = BN * 4 / NT;
    constexpr int SLOT = (BM + BN) * 32;  // ushorts per slot
    constexpr int BOFF = BM * 32;         // B region offset within slot

    const int tid  = threadIdx.x;
    const int lane = tid & 63;
    const int wave = tid >> 6;
    const int wm   = wave >> 1, wn = wave & 1;
    const int quad = lane >> 4;
    const int l16  = lane & 15;

#pragma unroll
    for (int i = 0; i < IM; i++)
#pragma unroll
        for (int j = 0; j < IN; j++) acc[i][j] = (floatx4){0.f, 0.f, 0.f, 0.f};

    const ushort_t* ga[SA];
    int la[SA];
#pragma unroll
    for (int s = 0; s < SA; s++) {
        int seg = tid + s * NT;
        int r = seg >> 2, c = (seg ^ r ^ (r >> 2)) & 3;
        ga[s] = A + (long)(r + tile_m) * lda + c * 8;
        la[s] = seg * 8;
    }
    const ushort_t* gb[SB];
    int lb[SB];
#pragma unroll
    for (int s = 0; s < SB; s++) {
        int seg = tid + s * NT;
        int r = seg >> 2, c = (seg ^ r ^ (r >> 2)) & 3;
        gb[s] = B + (long)(r + tile_n) * ldb + c * 8;
        lb[s] = BOFF + seg * 8;
    }

    const int nk = K >> 5;

    // prologue: issue ksteps 0 and 1 into slots 0 and 1
#pragma unroll
    for (int p = 0; p < 2; ++p) {
#pragma unroll
        for (int s = 0; s < SA; s++) async16(ga[s] + p * 32, buf + p * SLOT + la[s]);
#pragma unroll
        for (int s = 0; s < SB; s++) async16(gb[s] + p * 32, buf + p * SLOT + lb[s]);
    }

    int slot = 0, slot2 = 2;
    for (int k = 0; k < nk; ++k) {
        if (k + 1 < nk) {
            if constexpr (SA + SB == 4)
                asm volatile("s_waitcnt vmcnt(4)" ::: "memory");
            else if constexpr (SA + SB == 3)
                asm volatile("s_waitcnt vmcnt(3)" ::: "memory");
            else
                asm volatile("s_waitcnt vmcnt(2)" ::: "memory");
        } else {
            asm volatile("s_waitcnt vmcnt(0)" ::: "memory");
        }
        __builtin_amdgcn_s_barrier();
        asm volatile("" ::: "memory");

        if (k + 2 < nk) {
            const int koff = (k + 2) << 5;
            ushort_t* dst = buf + slot2 * SLOT;
#pragma unroll
            for (int s = 0; s < SA; s++) async16(ga[s] + koff, dst + la[s]);
#pragma unroll
            for (int s = 0; s < SB; s++) async16(gb[s] + koff, dst + lb[s]);
        }

        const ushort_t* as = buf + slot * SLOT;
        const ushort_t* bs = as + BOFF;
        bf16x8 af[IM], bfr[IN];
#pragma unroll
        for (int im = 0; im < IM; im++)
            af[im] = *(const bf16x8*)&as[sw(wm * IM * 16 + im * 16 + l16, quad)];
#pragma unroll
        for (int in = 0; in < IN; in++)
            bfr[in] = *(const bf16x8*)&bs[sw(wn * IN * 16 + in * 16 + l16, quad)];
#pragma unroll
        for (int im = 0; im < IM; im++)
#pragma unroll
            for (int in = 0; in < IN; in++)
                acc[im][in] = __builtin_amdgcn_mfma_f32_16x16x32_bf16(
                    af[im], bfr[in], acc[im][in], 0, 0, 0);

        slot  = (slot == 2) ? 0 : slot + 1;
        slot2 = (slot2 == 2) ? 0 : slot2 + 1;
    }
}

// ---------------------------------------------------------------------------
// prep: fp32->bf16 for x & W_v, zero lsum, transpose+cast Wq/Wk -> WqT/WkT
// block ranges: [0,8192) x | [8192,9216) wv | [9216,9224) lsum | [9224,9736) T
// ---------------------------------------------------------------------------
__global__ void prep_kernel(const float* __restrict__ x,
                            const float* __restrict__ wq,
                            const float* __restrict__ wk,
                            const float* __restrict__ wv,
                            ushort_t* __restrict__ xb,
                            ushort_t* __restrict__ wvb,
                            ushort_t* __restrict__ wqT,
                            ushort_t* __restrict__ wkT,
                            float* __restrict__ lsum) {
    const int bx = blockIdx.x;
    const int t = threadIdx.x;
    if (bx < 9216) {
        const float* src;
        ushort_t* dst;
        long g;
        if (bx < 8192) { src = x;  dst = xb;  g = ((long)bx * 256 + t) * 4; }
        else           { src = wv; dst = wvb; g = ((long)(bx - 8192) * 256 + t) * 4; }
        float4 v = *(const float4*)(src + g);
        ushort4 o;
        o.x = f2bf(v.x); o.y = f2bf(v.y); o.z = f2bf(v.z); o.w = f2bf(v.w);
        *(ushort4*)(dst + g) = o;
        return;
    }
    if (bx < 9224) {
        int idx = (bx - 9216) * 256 + t;  // [0,2048)
        ((float4*)lsum)[idx] = (float4){0.f, 0.f, 0.f, 0.f};
        return;
    }
    // transpose tiles
    const int tt = bx - 9224;           // [0,512)
    const float* src = (tt >= 256) ? wk : wq;
    ushort_t* dst = (tt >= 256) ? wkT : wqT;
    const int id = tt & 255;
    const int h0 = (id >> 4) * 64, d0 = (id & 15) * 64;
    __shared__ ushort_t tile[64 * 80];
    {
        int i = t >> 2, cg = (t & 3) << 4;
        const float4* p = (const float4*)(src + (long)(h0 + i) * 1024 + d0 + cg);
#pragma unroll
        for (int k = 0; k < 4; k++) {
            float4 v = p[k];
            ushort_t* q = &tile[i * 80 + cg + k * 4];
            q[0] = f2bf(v.x); q[1] = f2bf(v.y); q[2] = f2bf(v.z); q[3] = f2bf(v.w);
        }
    }
    __syncthreads();
    {
        int j = t >> 2, ig = (t & 3) << 4;
        ushort_t tmp[16];
#pragma unroll
        for (int k = 0; k < 16; k++) tmp[k] = tile[(ig + k) * 80 + j];
        ushort_t* o = dst + (long)(d0 + j) * 1024 + h0 + ig;
        *(uint4*)o = ((uint4*)tmp)[0];
        *(uint4*)(o + 8) = ((uint4*)tmp)[1];
    }
}

// ---------------------------------------------------------------------------
// gv: blocks [0,32) -> G = contraction of WkT/WqT over h (256x128 tiles)
//     blocks [32,288) -> V^T = Wv x^T (256x128 tiles)
// 512 threads, 8 waves.
// ---------------------------------------------------------------------------
__global__ __launch_bounds__(512, 4) void gv_kernel(
    const ushort_t* __restrict__ wkT, const ushort_t* __restrict__ wqT,
    const ushort_t* __restrict__ wvb, const ushort_t* __restrict__ xb,
    ushort_t* __restrict__ Gb, ushort_t* __restrict__ VTb) {

    __shared__ __align__(16) ushort_t buf[3 * 384 * 32];

    const ushort_t *A, *B;
    ushort_t* C;
    int ldc, tile_m, tile_n;
    if (blockIdx.x < 32) {   // G[e][d] = sum_h WkT[e][h] WqT[d][h]
        A = wkT; B = wqT; C = Gb; ldc = 1024;
        tile_m = (blockIdx.x >> 3) * 256;   // 4 m-tiles
        tile_n = (blockIdx.x & 7) * 128;    // 8 n-tiles
    } else {                 // VT[h][s] = sum_d Wv[h][d] x[s][d]
        int id = blockIdx.x - 32;           // [0,256)
        A = wvb; B = xb; C = VTb; ldc = 8192;
        tile_m = (id >> 6) * 256;           // 4 m-tiles
        tile_n = (id & 63) * 128;           // 64 n-tiles
    }

    floatx4 acc[4][4];
    gemm_core_p3<256, 128, 4, 4, 8>(A, 1024, B, 1024, 1024, tile_m, tile_n, buf, acc);

    const int lane = threadIdx.x & 63, wave = threadIdx.x >> 6;
    const int wm = wave >> 1, wn = wave & 1, quad = lane >> 4, l16 = lane & 15;
#pragma unroll
    for (int im = 0; im < 4; im++)
#pragma unroll
        for (int r = 0; r < 4; r++) {
            int row = tile_m + wm * 64 + im * 16 + quad * 4 + r;
#pragma unroll
            for (int in = 0; in < 4; in++) {
                int col = tile_n + wn * 64 + in * 16 + l16;
                C[(long)row * ldc + col] = f2bf(acc[im][in][r]);
            }
        }
}

// ---------------------------------------------------------------------------
// Y = x G^T  (M=8192, N=1024, K=1024; 128x128 tiles, 512 blocks = 2/CU)
// ---------------------------------------------------------------------------
__global__ __launch_bounds__(256) void y_kernel(
    const ushort_t* __restrict__ xb,
    const ushort_t* __restrict__ Gb,
    ushort_t* __restrict__ Yb) {

    __shared__ __align__(16) ushort_t buf[3 * 256 * 32];
    const int tile_m = blockIdx.y * 128;   // 64 m-tiles
    const int tile_n = blockIdx.x * 128;   // 8 n-tiles

    floatx4 acc[4][4];
    gemm_core_p3<128, 128, 4, 4, 4>(xb, 1024, Gb, 1024, 1024, tile_m, tile_n, buf, acc);

    const int lane = threadIdx.x & 63, wave = threadIdx.x >> 6;
    const int wm = wave >> 1, wn = wave & 1, quad = lane >> 4, l16 = lane & 15;
#pragma unroll
    for (int im = 0; im < 4; im++)
#pragma unroll
        for (int r = 0; r < 4; r++) {
            int row = tile_m + wm * 64 + im * 16 + quad * 4 + r;
#pragma unroll
            for (int in = 0; in < 4; in++) {
                int col = tile_n + wn * 64 + in * 16 + l16;
                Yb[(long)row * 1024 + col] = f2bf(acc[im][in][r]);
            }
        }
}

// ---------------------------------------------------------------------------
// P = exp(scale * Y x^T) per batch + fused row-sum atomics.
// 256x128 tiles, 512 thr, 72KB LDS -> exactly 2 blocks/CU; grid 512 = 2/CU.
// ---------------------------------------------------------------------------
__global__ __launch_bounds__(512, 4) void pexp_kernel(
    const ushort_t* __restrict__ Yb,
    const ushort_t* __restrict__ xb,
    ushort_t* __restrict__ Pb,
    float* __restrict__ lsum) {

    __shared__ __align__(16) ushort_t buf[3 * 384 * 32];

    const int z = blockIdx.z;
    const ushort_t* A = Yb + (long)z * 2097152;
    const ushort_t* B = xb + (long)z * 2097152;
    ushort_t* C = Pb + (long)z * 4194304;
    float* l = lsum + z * 2048;
    const int tile_m = blockIdx.y * 256;   // 8 m-tiles
    const int tile_n = blockIdx.x * 128;   // 16 n-tiles

    floatx4 acc[4][4];
    gemm_core_p3<256, 128, 4, 4, 8>(A, 1024, B, 1024, 1024, tile_m, tile_n, buf, acc);

    const float scale = 0.022097086912079608f;  // 1/sqrt(2048)
    const int lane = threadIdx.x & 63, wave = threadIdx.x >> 6;
    const int wm = wave >> 1, wn = wave & 1, quad = lane >> 4, l16 = lane & 15;
#pragma unroll
    for (int im = 0; im < 4; im++)
#pragma unroll
        for (int r = 0; r < 4; r++) {
            int row = tile_m + wm * 64 + im * 16 + quad * 4 + r;
            float psum = 0.f;
#pragma unroll
            for (int in = 0; in < 4; in++) {
                int col = tile_n + wn * 64 + in * 16 + l16;
                float e = __expf(acc[im][in][r] * scale);
                C[(long)row * 2048 + col] = f2bf(e);
                psum += e;
            }
            psum += __shfl_xor(psum, 1, 64);
            psum += __shfl_xor(psum, 2, 64);
            psum += __shfl_xor(psum, 4, 64);
            psum += __shfl_xor(psum, 8, 64);
            if (l16 == 0) atomicAdd(&l[row], psum);
        }
}

// ---------------------------------------------------------------------------
// out = (P V) / l per batch  (128x128 tiles, 512 blocks = 2/CU, 3 resident)
// ---------------------------------------------------------------------------
__global__ __launch_bounds__(256) void out_kernel(
    const ushort_t* __restrict__ Pb,
    const ushort_t* __restrict__ VTb,
    float* __restrict__ out,
    const float* __restrict__ lsum) {

    __shared__ __align__(16) ushort_t buf[3 * 256 * 32];

    const int z = blockIdx.z;
    const ushort_t* A = Pb + (long)z * 4194304;   // [2048][2048]
    const ushort_t* B = VTb + (long)z * 2048;     // ldb=8192, batch col slice
    float* C = out + (long)z * 2097152;
    const float* l = lsum + z * 2048;
    const int tile_m = blockIdx.y * 128;
    const int tile_n = blockIdx.x * 128;

    floatx4 acc[4][4];
    gemm_core_p3<128, 128, 4, 4, 4>(A, 2048, B, 8192, 2048, tile_m, tile_n, buf, acc);

    const int lane = threadIdx.x & 63, wave = threadIdx.x >> 6;
    const int wm = wave >> 1, wn = wave & 1, quad = lane >> 4, l16 = lane & 15;
#pragma unroll
    for (int im = 0; im < 4; im++)
#pragma unroll
        for (int r = 0; r < 4; r++) {
            int row = tile_m + wm * 64 + im * 16 + quad * 4 + r;
            float li = 1.0f / l[row];
#pragma unroll
            for (int in = 0; in < 4; in++) {
                int col = tile_n + wn * 64 + in * 16 + l16;
                C[(long)row * 1024 + col] = acc[im][in][r] * li;
            }
        }
}

// ---------------------------------------------------------------------------
extern "C" void kernel_launch(void* const* d_in, const int* in_sizes, int n_in,
                              void* d_out, int out_size, void* d_ws, size_t ws_size,
                              hipStream_t stream) {
    const float* x  = (const float*)d_in[0];
    const float* wq = (const float*)d_in[1];
    const float* wk = (const float*)d_in[2];
    const float* wv = (const float*)d_in[3];

    ushort_t* xb  = (ushort_t*)d_ws;          // [8192,1024] bf16
    ushort_t* wvb = xb  + 8388608;            // [1024,1024]
    ushort_t* wqT = wvb + 1048576;            // [1024,1024]  Wq^T bf16
    ushort_t* wkT = wqT + 1048576;            // [1024,1024]  Wk^T bf16
    ushort_t* Gb  = wkT + 1048576;            // [1024,1024]  G[e][d]
    ushort_t* Yb  = Gb  + 1048576;            // [8192,1024]  Y = x G^T
    ushort_t* VTb = Yb  + 8388608;            // [1024,8192]
    ushort_t* Pb  = VTb + 8388608;            // [4][2048][2048]
    float*    lsum = (float*)(Pb + 16777216); // [4][2048] fp32 row sums
    float*    out  = (float*)d_out;

    // 1) cvt x/wv + zero lsum + transpose wq/wk
    prep_kernel<<<9736, 256, 0, stream>>>(x, wq, wk, wv, xb, wvb, wqT, wkT, lsum);

    // 2) G (32 blocks) + V^T (256 blocks), 512 thr
    gv_kernel<<<288, 512, 0, stream>>>(wkT, wqT, wvb, xb, Gb, VTb);

    // 3) Y = x G^T (512 blocks = 2/CU)
    y_kernel<<<dim3(8, 64), 256, 0, stream>>>(xb, Gb, Yb);

    // 4) P = exp(scale * Y x^T) + row sums (512 blocks = 2/CU, even residency)
    pexp_kernel<<<dim3(16, 8, 4), 512, 0, stream>>>(Yb, xb, Pb, lsum);

    // 5) out = (P V) / l (512 blocks = 2/CU)
    out_kernel<<<dim3(8, 16, 4), 256, 0, stream>>>(Pb, VTb, out, lsum);
}